// Round 2
// baseline (253.102 us; speedup 1.0000x reference)
//
#include <hip/hip_runtime.h>
#include <cmath>

typedef _Float16 half8 __attribute__((ext_vector_type(8)));
typedef float f32x4 __attribute__((ext_vector_type(4)));

#define GLD_LDS16(gptr, lptr)                                                  \
  __builtin_amdgcn_global_load_lds(                                            \
      (const __attribute__((address_space(1))) void*)(gptr),                   \
      (__attribute__((address_space(3))) void*)(lptr), 16, 0, 0)

#define MEMFENCE asm volatile("" ::: "memory")

// ---------------- f32 -> f16 conversion (vectorized, grid-stride) -----------
__global__ void cvt_f32_to_f16(const float* __restrict__ in,
                               _Float16* __restrict__ out, long n) {
  long stride = (long)gridDim.x * blockDim.x * 8;
  for (long i = ((long)blockIdx.x * blockDim.x + threadIdx.x) * 8; i < n;
       i += stride) {
    const float4* p = (const float4*)(in + i);
    float4 a = p[0];
    float4 b = p[1];
    half8 h = {(_Float16)a.x, (_Float16)a.y, (_Float16)a.z, (_Float16)a.w,
               (_Float16)b.x, (_Float16)b.y, (_Float16)b.z, (_Float16)b.w};
    *(half8*)(out + i) = h;
  }
}

// ---------------- GEMM: C[m,n] = sum_k A[m,k]*B[n,k]  (both K-major) --------
// EPI: 0 = acc+bias -> f16 ; 1 = 0.5*tanh(acc+bias) -> f16 ; 2 = acc+bias -> f32
// BM=256, BN=128, BK=64, 512 threads = 8 waves (4M x 2N), 64x64 per wave.
// T3+T4: double-buffered LDS, counted vmcnt(6) (next tile's loads span the
// barrier). T2: chunk^row&7 XOR swizzle via pre-swizzled global source
// (linear LDS dest as global_load_lds requires) + identical XOR on ds_read.
// T5: setprio around MFMA clusters.
template <int EPI>
__global__ __launch_bounds__(512, 2) void gemm256(
    const _Float16* __restrict__ A, const _Float16* __restrict__ Bm,
    const float* __restrict__ bias, void* __restrict__ Cout, int N, int K) {
  __shared__ _Float16 As[2][256 * 64];
  __shared__ _Float16 Bs[2][128 * 64];

  const int tid = threadIdx.x;
  const int lane = tid & 63;
  const int wave = tid >> 6;
  const int brow = blockIdx.y * 256;
  const int bcol = blockIdx.x * 128;
  const int wr = (wave >> 1) * 64;  // wave row offset (4 M-waves)
  const int wc = (wave & 1) * 64;   // wave col offset (2 N-waves)

  // ---- staging geometry: 512 thr x 16B = 64 rows x 64 cols f16 per issue.
  // A: 4 issues (256 rows), B: 2 issues (128 rows).
  const int sr = tid >> 3;                      // 0..63 row within issue group
  const int sc = ((tid & 7) ^ (sr & 7)) * 8;    // swizzled source col (T2)
  const _Float16* Ag = A + (size_t)(brow + sr) * K + sc;
  const _Float16* Bg = Bm + (size_t)(bcol + sr) * K + sc;
  const int ldst = tid * 8;  // linear LDS dest (wave-uniform base + lane*16B)

  // ---- MFMA fragment geometry (16x16x32): row=lane&15, k=(lane>>4)*8
  const int frow = lane & 15;
  const int hi = lane >> 4;
  const int xr = lane & 7;  // row XOR for swizzled ds_read

  f32x4 acc[4][4] = {};

  const int nt = K >> 6;

  auto stage = [&](int buf, int t) {
    const _Float16* ag = Ag + t * 64;
    const _Float16* bg = Bg + t * 64;
    _Float16* al = &As[buf][ldst];
    _Float16* bl = &Bs[buf][ldst];
#pragma unroll
    for (int i = 0; i < 4; i++)
      GLD_LDS16(ag + (size_t)i * 64 * K, al + i * 4096);
#pragma unroll
    for (int i = 0; i < 2; i++)
      GLD_LDS16(bg + (size_t)i * 64 * K, bl + i * 4096);
  };

  stage(0, 0);

  for (int t = 0; t < nt; ++t) {
    const int cur = t & 1;
    if (t + 1 < nt) {
      stage(cur ^ 1, t + 1);
      asm volatile("s_waitcnt vmcnt(6)" ::: "memory");  // tile t landed; t+1 in flight
    } else {
      asm volatile("s_waitcnt vmcnt(0)" ::: "memory");
    }
    __builtin_amdgcn_s_barrier();
    MEMFENCE;  // keep ds_reads below the barrier

#pragma unroll
    for (int kk = 0; kk < 2; kk++) {
      half8 a[4], b[4];
#pragma unroll
      for (int m = 0; m < 4; m++) {
        const int row = wr + m * 16 + frow;
        const int ch = ((kk * 4 + hi) ^ xr) * 8;
        a[m] = *(const half8*)&As[cur][row * 64 + ch];
      }
#pragma unroll
      for (int n = 0; n < 4; n++) {
        const int row = wc + n * 16 + frow;
        const int ch = ((kk * 4 + hi) ^ xr) * 8;
        b[n] = *(const half8*)&Bs[cur][row * 64 + ch];
      }
      __builtin_amdgcn_s_setprio(1);
#pragma unroll
      for (int m = 0; m < 4; m++)
#pragma unroll
        for (int n = 0; n < 4; n++)
          acc[m][n] = __builtin_amdgcn_mfma_f32_16x16x32_f16(a[m], b[n],
                                                             acc[m][n], 0, 0, 0);
      __builtin_amdgcn_s_setprio(0);
    }

    MEMFENCE;  // keep ds_reads above the end barrier (buffer recycled next iter)
    __builtin_amdgcn_s_barrier();
  }

  // epilogue: C/D layout col = lane&15, row = (lane>>4)*4 + reg
  const int r0 = hi * 4;
  const int c0 = frow;
#pragma unroll
  for (int n = 0; n < 4; n++) {
    const int col = bcol + wc + n * 16 + c0;
    const float bv = bias[col];
#pragma unroll
    for (int m = 0; m < 4; m++) {
#pragma unroll
      for (int r = 0; r < 4; r++) {
        const int row = brow + wr + m * 16 + r0 + r;
        float v = acc[m][n][r] + bv;
        if (EPI == 1) v = 0.5f * tanhf(v);
        if (EPI == 2)
          ((float*)Cout)[(size_t)row * N + col] = v;
        else
          ((_Float16*)Cout)[(size_t)row * N + col] = (_Float16)v;
      }
    }
  }
}

// ---------------------------------------------------------------------------
extern "C" void kernel_launch(void* const* d_in, const int* in_sizes, int n_in,
                              void* d_out, int out_size, void* d_ws,
                              size_t ws_size, hipStream_t stream) {
  (void)in_sizes;
  (void)n_in;
  (void)out_size;
  (void)ws_size;

  const float* x = (const float*)d_in[0];        // [4096,1024]
  const float* W_embed = (const float*)d_in[1];  // [2048,1024]
  const float* b_embed = (const float*)d_in[2];  // [2048]
  const float* W_layers = (const float*)d_in[3]; // [3,2048,2048]
  const float* b_layers = (const float*)d_in[4]; // [3,2048]
  const float* W_head = (const float*)d_in[5];   // [1024,2048]
  const float* b_head = (const float*)d_in[6];   // [1024]

  const int B = 4096, I = 1024, H = 2048, O = 1024;

  char* w = (char*)d_ws;
  auto carve = [&](size_t bytes) {
    char* p = w;
    w += (bytes + 255) & ~(size_t)255;
    return p;
  };
  _Float16* xh = (_Float16*)carve((size_t)B * I * 2);
  _Float16* Weh = (_Float16*)carve((size_t)H * I * 2);
  _Float16* Wlh = (_Float16*)carve((size_t)3 * H * H * 2);
  _Float16* Whh = (_Float16*)carve((size_t)O * H * 2);
  _Float16* bufE = (_Float16*)carve((size_t)B * H * 2);
  _Float16* bufA = (_Float16*)carve((size_t)B * H * 2);

  cvt_f32_to_f16<<<1024, 256, 0, stream>>>(x, xh, (long)B * I);
  cvt_f32_to_f16<<<1024, 256, 0, stream>>>(W_embed, Weh, (long)H * I);
  cvt_f32_to_f16<<<2048, 256, 0, stream>>>(W_layers, Wlh, (long)3 * H * H);
  cvt_f32_to_f16<<<1024, 256, 0, stream>>>(W_head, Whh, (long)O * H);

  dim3 blk(512);
  // x_emb = x @ W_embed^T + b_embed            [B,H], f16
  gemm256<0><<<dim3(H / 128, B / 256), blk, 0, stream>>>(xh, Weh, b_embed,
                                                         bufE, H, I);
  // h0 = 0.5*tanh(x_emb @ W0^T + b0)           [B,H], f16
  gemm256<1><<<dim3(H / 128, B / 256), blk, 0, stream>>>(bufE, Wlh, b_layers,
                                                         bufA, H, H);
  // h1 = 0.5*tanh(h0 @ W1^T + b1)              [B,H], f16
  gemm256<1><<<dim3(H / 128, B / 256), blk, 0, stream>>>(
      bufA, Wlh + (size_t)H * H, b_layers + H, bufE, H, H);
  // h2 = 0.5*tanh(h1 @ W2^T + b2)              [B,H], f16
  gemm256<1><<<dim3(H / 128, B / 256), blk, 0, stream>>>(
      bufE, Wlh + (size_t)2 * H * H, b_layers + 2 * H, bufA, H, H);
  // out = h2 @ W_head^T + b_head               [B,O], f32
  gemm256<2><<<dim3(O / 128, B / 256), blk, 0, stream>>>(bufA, Whh, b_head,
                                                         d_out, O, H);
}

// Round 3
// 224.546 us; speedup vs baseline: 1.1272x; 1.1272x over previous
//
#include <hip/hip_runtime.h>
#include <cmath>

typedef _Float16 half8 __attribute__((ext_vector_type(8)));
typedef float f32x4 __attribute__((ext_vector_type(4)));

#define GLD_LDS16(gptr, lptr)                                                  \
  __builtin_amdgcn_global_load_lds(                                            \
      (const __attribute__((address_space(1))) void*)(gptr),                   \
      (__attribute__((address_space(3))) void*)(lptr), 16, 0, 0)

#define MEMFENCE asm volatile("" ::: "memory")

// ---------------- f32 -> f16 conversion (vectorized, grid-stride) -----------
__global__ void cvt_f32_to_f16(const float* __restrict__ in,
                               _Float16* __restrict__ out, long n) {
  long stride = (long)gridDim.x * blockDim.x * 8;
  for (long i = ((long)blockIdx.x * blockDim.x + threadIdx.x) * 8; i < n;
       i += stride) {
    const float4* p = (const float4*)(in + i);
    float4 a = p[0];
    float4 b = p[1];
    half8 h = {(_Float16)a.x, (_Float16)a.y, (_Float16)a.z, (_Float16)a.w,
               (_Float16)b.x, (_Float16)b.y, (_Float16)b.z, (_Float16)b.w};
    *(half8*)(out + i) = h;
  }
}

// ---------------- GEMM: C[m,n] = sum_k A[m,k]*B[n,k]  (both K-major) --------
// EPI: 0 = acc+bias -> f16 ; 1 = 0.5*tanh(acc+bias) -> f16 ; 2 = acc+bias -> f32
// NW:  B-fragments per wave. BN = NW*32 (4 -> BN=128, 2 -> BN=64).
// BM=256, BK=64, 512 threads = 8 waves (4M x 2N), wave tile 64 x (BN/2).
// Fine-phase schedule (m201-style, 2 phases/K-tile):
//   phase = { ds_read frags (kk half) || stage partial next tile
//             -> s_barrier -> setprio(1) MFMA cluster setprio(0) -> s_barrier }
// Raw s_barrier everywhere (no implicit vmcnt drain); single vmcnt(0) per
// K-tile placed ~2 phases after the stage issues. T2 XOR swizzle both sides.
// 1-D grid + bijective XCD-chunk swizzle (nb % 8 == 0).
template <int EPI, int NW>
__global__ __launch_bounds__(512, 2) void gemm8p(
    const _Float16* __restrict__ A, const _Float16* __restrict__ Bm,
    const float* __restrict__ bias, void* __restrict__ Cout, int N, int K) {
  constexpr int BN = NW * 32;
  constexpr int BLOADS = BN / 64;  // 64-row staging issues for B
  __shared__ _Float16 As[2][256 * 64];
  __shared__ _Float16 Bs[2][BN * 64];

  const int tid = threadIdx.x;
  const int lane = tid & 63;
  const int wave = tid >> 6;

  // XCD-aware chunked swizzle (requires gridDim.x % 8 == 0 — true here)
  const int nb = gridDim.x;
  const int nxb = N / BN;
  const int swz = ((int)blockIdx.x & 7) * (nb >> 3) + ((int)blockIdx.x >> 3);
  const int brow = (swz / nxb) * 256;
  const int bcol = (swz % nxb) * BN;

  const int wr = (wave >> 1) * 64;        // 4 M-waves
  const int wc = (wave & 1) * (BN / 2);   // 2 N-waves

  // staging: 512 thr x 16B covers 64 rows x 64 f16 cols per issue.
  const int sr = tid >> 3;
  const int sc = ((tid & 7) ^ (sr & 7)) * 8;  // T2: pre-swizzled source col
  const _Float16* Ag = A + (size_t)(brow + sr) * K + sc;
  const _Float16* Bg = Bm + (size_t)(bcol + sr) * K + sc;
  const int ldst = tid * 8;  // linear LDS dest (required by global_load_lds)

  // MFMA fragment geometry (16x16x32): row=lane&15, k-half=(lane>>4)*8
  const int frow = lane & 15;
  const int hi = lane >> 4;
  const int xr = lane & 7;  // read-side XOR (matches source swizzle)

  f32x4 acc[4][NW];
#pragma unroll
  for (int m = 0; m < 4; m++)
#pragma unroll
    for (int n = 0; n < NW; n++) acc[m][n] = f32x4{0.f, 0.f, 0.f, 0.f};

  const int nt = K >> 6;

  auto stageA = [&](int buf, int t, int i0, int i1) {
    const _Float16* ag = Ag + t * 64;
    _Float16* al = &As[buf][ldst];
#pragma unroll
    for (int i = 0; i < 4; i++)
      if (i >= i0 && i < i1) GLD_LDS16(ag + (size_t)i * 64 * K, al + i * 4096);
  };
  auto stageB = [&](int buf, int t) {
    const _Float16* bg = Bg + t * 64;
    _Float16* bl = &Bs[buf][ldst];
#pragma unroll
    for (int i = 0; i < BLOADS; i++)
      GLD_LDS16(bg + (size_t)i * 64 * K, bl + i * 4096);
  };

  // prologue: stage tile 0, drain, barrier
  stageA(0, 0, 0, 4);
  stageB(0, 0);
  asm volatile("s_waitcnt vmcnt(0)" ::: "memory");
  __builtin_amdgcn_s_barrier();
  MEMFENCE;

  for (int t = 0; t < nt; ++t) {
    const int cur = t & 1;
    const bool pf = (t + 1 < nt);

    // ================= phase 1 : kk = 0 =================
    half8 a0[4], b0[NW];
    {
      const int ch = (hi ^ xr) * 8;
#pragma unroll
      for (int m = 0; m < 4; m++)
        a0[m] = *(const half8*)&As[cur][(wr + m * 16 + frow) * 64 + ch];
#pragma unroll
      for (int n = 0; n < NW; n++)
        b0[n] = *(const half8*)&Bs[cur][(wc + n * 16 + frow) * 64 + ch];
    }
    if (pf) stageA(cur ^ 1, t + 1, 0, 3);  // 3 of 4 A-issues for t+1
    MEMFENCE;
    __builtin_amdgcn_s_barrier();
    MEMFENCE;
    __builtin_amdgcn_s_setprio(1);
#pragma unroll
    for (int m = 0; m < 4; m++)
#pragma unroll
      for (int n = 0; n < NW; n++)
        acc[m][n] =
            __builtin_amdgcn_mfma_f32_16x16x32_f16(a0[m], b0[n], acc[m][n], 0, 0, 0);
    __builtin_amdgcn_s_setprio(0);
    MEMFENCE;
    __builtin_amdgcn_s_barrier();
    MEMFENCE;

    // ================= phase 2 : kk = 1 =================
    half8 a1[4], b1[NW];
    {
      const int ch = ((4 + hi) ^ xr) * 8;
#pragma unroll
      for (int m = 0; m < 4; m++)
        a1[m] = *(const half8*)&As[cur][(wr + m * 16 + frow) * 64 + ch];
#pragma unroll
      for (int n = 0; n < NW; n++)
        b1[n] = *(const half8*)&Bs[cur][(wc + n * 16 + frow) * 64 + ch];
    }
    if (pf) {
      stageA(cur ^ 1, t + 1, 3, 4);  // last A-issue + B for t+1
      stageB(cur ^ 1, t + 1);
    }
    MEMFENCE;
    __builtin_amdgcn_s_barrier();
    MEMFENCE;
    __builtin_amdgcn_s_setprio(1);
#pragma unroll
    for (int m = 0; m < 4; m++)
#pragma unroll
      for (int n = 0; n < NW; n++)
        acc[m][n] =
            __builtin_amdgcn_mfma_f32_16x16x32_f16(a1[m], b1[n], acc[m][n], 0, 0, 0);
    __builtin_amdgcn_s_setprio(0);
    if (pf) asm volatile("s_waitcnt vmcnt(0)" ::: "memory");  // t+1 staged (issued 2 phases ago)
    MEMFENCE;
    __builtin_amdgcn_s_barrier();  // K-tile boundary: buf[cur^1] ready, buf[cur] free
    MEMFENCE;
  }

  // epilogue: C/D layout col = lane&15, row = (lane>>4)*4 + reg
  const int r0 = hi * 4;
  const int c0 = frow;
#pragma unroll
  for (int n = 0; n < NW; n++) {
    const int col = bcol + wc + n * 16 + c0;
    const float bv = bias[col];
#pragma unroll
    for (int m = 0; m < 4; m++) {
#pragma unroll
      for (int r = 0; r < 4; r++) {
        const int row = brow + wr + m * 16 + r0 + r;
        float v = acc[m][n][r] + bv;
        if (EPI == 1) v = 0.5f * tanhf(v);
        if (EPI == 2)
          ((float*)Cout)[(size_t)row * N + col] = v;
        else
          ((_Float16*)Cout)[(size_t)row * N + col] = (_Float16)v;
      }
    }
  }
}

// ---------------------------------------------------------------------------
extern "C" void kernel_launch(void* const* d_in, const int* in_sizes, int n_in,
                              void* d_out, int out_size, void* d_ws,
                              size_t ws_size, hipStream_t stream) {
  (void)in_sizes;
  (void)n_in;
  (void)out_size;
  (void)ws_size;

  const float* x = (const float*)d_in[0];        // [4096,1024]
  const float* W_embed = (const float*)d_in[1];  // [2048,1024]
  const float* b_embed = (const float*)d_in[2];  // [2048]
  const float* W_layers = (const float*)d_in[3]; // [3,2048,2048]
  const float* b_layers = (const float*)d_in[4]; // [3,2048]
  const float* W_head = (const float*)d_in[5];   // [1024,2048]
  const float* b_head = (const float*)d_in[6];   // [1024]

  const int B = 4096, I = 1024, H = 2048, O = 1024;

  char* w = (char*)d_ws;
  auto carve = [&](size_t bytes) {
    char* p = w;
    w += (bytes + 255) & ~(size_t)255;
    return p;
  };
  _Float16* xh = (_Float16*)carve((size_t)B * I * 2);
  _Float16* Weh = (_Float16*)carve((size_t)H * I * 2);
  _Float16* Wlh = (_Float16*)carve((size_t)3 * H * H * 2);
  _Float16* Whh = (_Float16*)carve((size_t)O * H * 2);
  _Float16* bufE = (_Float16*)carve((size_t)B * H * 2);
  _Float16* bufA = (_Float16*)carve((size_t)B * H * 2);

  cvt_f32_to_f16<<<1024, 256, 0, stream>>>(x, xh, (long)B * I);
  cvt_f32_to_f16<<<1024, 256, 0, stream>>>(W_embed, Weh, (long)H * I);
  cvt_f32_to_f16<<<2048, 256, 0, stream>>>(W_layers, Wlh, (long)3 * H * H);
  cvt_f32_to_f16<<<1024, 256, 0, stream>>>(W_head, Whh, (long)O * H);

  dim3 blk(512);
  const int nbHH = (H / 128) * (B / 256);  // 256 blocks
  const int nbHO = (O / 64) * (B / 256);   // 256 blocks (BN=64 head)

  // x_emb = x @ W_embed^T + b_embed            [B,H], f16
  gemm8p<0, 4><<<nbHH, blk, 0, stream>>>(xh, Weh, b_embed, bufE, H, I);
  // h0 = 0.5*tanh(x_emb @ W0^T + b0)           [B,H], f16
  gemm8p<1, 4><<<nbHH, blk, 0, stream>>>(bufE, Wlh, b_layers, bufA, H, H);
  // h1 = 0.5*tanh(h0 @ W1^T + b1)              [B,H], f16
  gemm8p<1, 4><<<nbHH, blk, 0, stream>>>(bufA, Wlh + (size_t)H * H,
                                         b_layers + H, bufE, H, H);
  // h2 = 0.5*tanh(h1 @ W2^T + b2)              [B,H], f16
  gemm8p<1, 4><<<nbHH, blk, 0, stream>>>(bufE, Wlh + (size_t)2 * H * H,
                                         b_layers + 2 * H, bufA, H, H);
  // out = h2 @ W_head^T + b_head               [B,O], f32  (BN=64 -> full grid)
  gemm8p<2, 2><<<nbHO, blk, 0, stream>>>(bufA, Whh, b_head, d_out, O, H);
}